// Round 20
// baseline (84.084 us; speedup 1.0000x reference)
//
#include <hip/hip_runtime.h>
#include <math.h>

// B,N,T,F = 32,512,12,64
#define NN 512
#define TT 12
#define FF 64

typedef float  f32x4   __attribute__((ext_vector_type(4)));
typedef float  f32x16  __attribute__((ext_vector_type(16)));
typedef short  short2v __attribute__((ext_vector_type(2)));
typedef short  short4v __attribute__((ext_vector_type(4)));
typedef short  short8v __attribute__((ext_vector_type(8)));
typedef _Float16 h16x4 __attribute__((ext_vector_type(4)));
typedef _Float16 h16x8 __attribute__((ext_vector_type(8)));
typedef unsigned int u32;
typedef u32    u32x4   __attribute__((ext_vector_type(4)));

static __device__ __forceinline__ u32 pkrtz(float a, float b) {
    u32 p;
    asm("v_cvt_pkrtz_f16_f32 %0, %1, %2" : "=v"(p) : "v"(a), "v"(b));
    return p;   // low16 = fp16(a), high16 = fp16(b)
}
static __device__ __forceinline__ void cvt4h(f32x4 v, short4v& h, short4v& lo) {
    h16x4 hh, ll;
    #pragma unroll
    for (int j = 0; j < 4; ++j) {
        _Float16 a = (_Float16)v[j];
        hh[j] = a;
        ll[j] = (_Float16)(v[j] - (float)a);
    }
    h  = __builtin_bit_cast(short4v, hh);
    lo = __builtin_bit_cast(short4v, ll);
}
static __device__ __forceinline__ short4v cvt4hi(f32x4 v) {
    h16x4 hh;
    #pragma unroll
    for (int j = 0; j < 4; ++j) hh[j] = (_Float16)v[j];
    return __builtin_bit_cast(short4v, hh);
}
static __device__ __forceinline__ short8v cat44(short4v a, short4v b) {
    return __builtin_shufflevector(a, b, 0, 1, 2, 3, 4, 5, 6, 7);
}
static __device__ __forceinline__ f32x16 mfmah(short8v a, short8v b, f32x16 c) {
    return __builtin_amdgcn_mfma_f32_32x32x16_f16(
        __builtin_bit_cast(h16x8, a), __builtin_bit_cast(h16x8, b), c, 0, 0, 0);
}

// LDS: two K-tile buffers (each: sKH [64][68] @+0, sKTH @+8704 = 17408 B)
//      buf0 @0, buf1 @17408, linv f32[256] @34816.  Total 35840.
// 8-wave WGs share the buffers (amortization = the occupancy lever).
// Epilogue: sA [256][68] fp16 @0 (exactly fills both buffers).
#define BUFSZ 17408
#define SMEM_BYTES 35840

__global__ __launch_bounds__(512, 4)   // cap 128 >> natural ~110: no allocator pressure
void sgcn20(const float* __restrict__ x, const float* __restrict__ adj,
            const float* __restrict__ W, float* __restrict__ out)
{
    __shared__ __align__(16) char smem[SMEM_BYTES];
    char* sA = smem;
    float* linvLDS = (float*)(smem + 2 * BUFSZ);

    // XCD-grouped swizzle: 2 WGs per (b,t) adjacent on one XCD; grid 768 = 8*96
    const int d   = blockIdx.x;
    const int xcd = d & 7;
    const int s   = d >> 3;               // 0..95
    const int G   = xcd + 8 * (s >> 1);   // 0..383 = b*12 + t
    const int mem = s & 1;
    const int t = G % TT, b = G / TT;
    const int n0 = mem * 256;

    const int tid = threadIdx.x;
    const int w   = tid >> 6;             // wave 0..7 -> n-rows 32w..32w+31
    const int l31 = tid & 31;
    const int hi2 = (tid >> 5) & 1;
    const int fq  = tid & 15;             // staging: f-quad (floats 4fq..4fq+3)
    const int mq  = tid >> 4;             // staging: row pair (rows 2mq, 2mq+1)
    const int myn = n0 + 32 * w + l31;    // this lane's n (S^T col / PV A row)

    const float K2 = 0.18033688011112042f;   // 0.125 * log2(e)
    const float SH2 = 8.656170245333781f;    // 6*log2(e): shifted maxless softmax

    // ---- prologue: xn fragments, fp16 hi only (1-term QK) ----
    const float* xnrow = x + ((size_t)(b * NN + myn) * TT + t) * FF;
    short8v xnH[4];
    #pragma unroll
    for (int ks = 0; ks < 4; ++ks) {
        f32x4 a0 = *(const f32x4*)(xnrow + ks * 16 + hi2 * 8);
        f32x4 a1 = *(const f32x4*)(xnrow + ks * 16 + hi2 * 8 + 4);
        xnH[ks] = cat44(cvt4hi(a0), cvt4hi(a1));
    }

    short4v sh0, sh1;   // staging conversion registers (2 rows/thread)

#define STAGE_LOAD(M0, R0, R1)                                                 \
    {                                                                          \
        const float* xs = x + ((size_t)(b * NN + (M0) + 2 * mq) * TT + t) * FF + 4 * fq; \
        R0 = *(const f32x4*)(xs);                                              \
        R1 = *(const f32x4*)(xs + TT * FF);                                    \
    }

#define STAGE_CONVERT(L0, L1)                                                  \
    { sh0 = cvt4hi(L0); sh1 = cvt4hi(L1); }

#define STAGE_LDS_WRITE(DST)                                                   \
  {                                                                            \
    char* dKH = (DST);                                                         \
    char* dKT = (DST) + 8704;                                                  \
    *(short4v*)(dKH + ((2*mq+0)*68 + 4*fq) * 2) = sh0;                         \
    *(short4v*)(dKH + ((2*mq+1)*68 + 4*fq) * 2) = sh1;                         \
    _Pragma("unroll")                                                          \
    for (int j = 0; j < 4; ++j) {                                              \
        short2v th; th[0] = sh0[j]; th[1] = sh1[j];                            \
        *(short2v*)(dKT + ((4*fq+j)*68 + 2*mq) * 2) = th;                      \
    }                                                                          \
  }

// one tile: QK0 SM0 PV01 QK1 SM1 PV23 (R19-verified, shuffle-free).
// P->A-frag native pack order; PV B-frag reads V with matching k-permutation:
//   A elem j (half hi2) = m (j<4 ? j : j+4) + 4*hi2
//   => B reads V rows base + 4*hi2 + {0..3} and base + 8 + 4*hi2 + {0..3}
#define PROCESS_TILE(BASE, M0)                                                 \
  {                                                                            \
    const char* bKH = (BASE);                                                  \
    const char* bKT = (BASE) + 8704;                                           \
    const float* arow0 = adj + (size_t)myn * NN + (M0) + 4 * hi2;              \
    f32x4 a00 = *(const f32x4*)(arow0);                                        \
    f32x4 a01 = *(const f32x4*)(arow0 + 8);                                    \
    f32x4 a02 = *(const f32x4*)(arow0 + 16);                                   \
    f32x4 a03 = *(const f32x4*)(arow0 + 24);                                   \
    short8v pa[4];                                                             \
    f32x16 sc;                                                                 \
    _Pragma("unroll")                                                          \
    for (int i = 0; i < 16; ++i) sc[i] = 0.f;                                  \
    _Pragma("unroll")                                                          \
    for (int ks = 0; ks < 4; ++ks) {                                           \
        short4v k0 = *(const short4v*)(bKH + (l31 * 68 + ks*16 + hi2*8) * 2);  \
        short4v k1 = *(const short4v*)(bKH + (l31 * 68 + ks*16 + hi2*8 + 4) * 2); \
        sc = mfmah(cat44(k0, k1), xnH[ks], sc);                                \
    }                                                                          \
    const float* arow1 = adj + (size_t)myn * NN + (M0) + 32 + 4 * hi2;         \
    f32x4 a10 = *(const f32x4*)(arow1);                                        \
    f32x4 a11 = *(const f32x4*)(arow1 + 8);                                    \
    f32x4 a12 = *(const f32x4*)(arow1 + 16);                                   \
    f32x4 a13 = *(const f32x4*)(arow1 + 24);                                   \
    {                                                                          \
        float p[16];                                                           \
        _Pragma("unroll")                                                      \
        for (int r = 0; r < 16; ++r) {                                         \
            p[r] = __builtin_amdgcn_exp2f(sc[r] * K2 - SH2);                   \
            lp4[r & 3] += p[r];                                                \
        }                                                                      \
        p[0] *= a00[0]; p[1] *= a00[1]; p[2]  *= a00[2]; p[3]  *= a00[3];      \
        p[4] *= a01[0]; p[5] *= a01[1]; p[6]  *= a01[2]; p[7]  *= a01[3];      \
        p[8] *= a02[0]; p[9] *= a02[1]; p[10] *= a02[2]; p[11] *= a02[3];      \
        p[12]*= a03[0]; p[13]*= a03[1]; p[14] *= a03[2]; p[15] *= a03[3];      \
        u32x4 e, o;                                                            \
        e[0] = pkrtz(p[0],  p[1]);  e[1] = pkrtz(p[2],  p[3]);                 \
        e[2] = pkrtz(p[4],  p[5]);  e[3] = pkrtz(p[6],  p[7]);                 \
        o[0] = pkrtz(p[8],  p[9]);  o[1] = pkrtz(p[10], p[11]);                \
        o[2] = pkrtz(p[12], p[13]); o[3] = pkrtz(p[14], p[15]);                \
        pa[0] = __builtin_bit_cast(short8v, e);                                \
        pa[1] = __builtin_bit_cast(short8v, o);                                \
    }                                                                          \
    {                                                                          \
        short4v v0 = *(const short4v*)(bKT + (l31 * 68 + 4*hi2) * 2);          \
        short4v v1 = *(const short4v*)(bKT + (l31 * 68 + 8 + 4*hi2) * 2);      \
        agg0 = mfmah(pa[0], cat44(v0, v1), agg0);                              \
        short4v w0 = *(const short4v*)(bKT + ((32 + l31) * 68 + 4*hi2) * 2);   \
        short4v w1 = *(const short4v*)(bKT + ((32 + l31) * 68 + 8 + 4*hi2) * 2); \
        agg1 = mfmah(pa[0], cat44(w0, w1), agg1);                              \
        short4v v2 = *(const short4v*)(bKT + (l31 * 68 + 16 + 4*hi2) * 2);     \
        short4v v3 = *(const short4v*)(bKT + (l31 * 68 + 16 + 8 + 4*hi2) * 2); \
        agg0 = mfmah(pa[1], cat44(v2, v3), agg0);                              \
        short4v w2 = *(const short4v*)(bKT + ((32 + l31) * 68 + 16 + 4*hi2) * 2); \
        short4v w3 = *(const short4v*)(bKT + ((32 + l31) * 68 + 16 + 8 + 4*hi2) * 2); \
        agg1 = mfmah(pa[1], cat44(w2, w3), agg1);                              \
    }                                                                          \
    _Pragma("unroll")                                                          \
    for (int i = 0; i < 16; ++i) sc[i] = 0.f;                                  \
    _Pragma("unroll")                                                          \
    for (int ks = 0; ks < 4; ++ks) {                                           \
        short4v k0 = *(const short4v*)(bKH + ((32 + l31) * 68 + ks*16 + hi2*8) * 2); \
        short4v k1 = *(const short4v*)(bKH + ((32 + l31) * 68 + ks*16 + hi2*8 + 4) * 2); \
        sc = mfmah(cat44(k0, k1), xnH[ks], sc);                                \
    }                                                                          \
    {                                                                          \
        float p[16];                                                           \
        _Pragma("unroll")                                                      \
        for (int r = 0; r < 16; ++r) {                                         \
            p[r] = __builtin_amdgcn_exp2f(sc[r] * K2 - SH2);                   \
            lp4[r & 3] += p[r];                                                \
        }                                                                      \
        p[0] *= a10[0]; p[1] *= a10[1]; p[2]  *= a10[2]; p[3]  *= a10[3];      \
        p[4] *= a11[0]; p[5] *= a11[1]; p[6]  *= a11[2]; p[7]  *= a11[3];      \
        p[8] *= a12[0]; p[9] *= a12[1]; p[10] *= a12[2]; p[11] *= a12[3];      \
        p[12]*= a13[0]; p[13]*= a13[1]; p[14] *= a13[2]; p[15] *= a13[3];      \
        u32x4 e, o;                                                            \
        e[0] = pkrtz(p[0],  p[1]);  e[1] = pkrtz(p[2],  p[3]);                 \
        e[2] = pkrtz(p[4],  p[5]);  e[3] = pkrtz(p[6],  p[7]);                 \
        o[0] = pkrtz(p[8],  p[9]);  o[1] = pkrtz(p[10], p[11]);                \
        o[2] = pkrtz(p[12], p[13]); o[3] = pkrtz(p[14], p[15]);                \
        pa[2] = __builtin_bit_cast(short8v, e);                                \
        pa[3] = __builtin_bit_cast(short8v, o);                                \
    }                                                                          \
    {                                                                          \
        short4v v0 = *(const short4v*)(bKT + (l31 * 68 + 32 + 4*hi2) * 2);     \
        short4v v1 = *(const short4v*)(bKT + (l31 * 68 + 32 + 8 + 4*hi2) * 2); \
        agg0 = mfmah(pa[2], cat44(v0, v1), agg0);                              \
        short4v w0 = *(const short4v*)(bKT + ((32 + l31) * 68 + 32 + 4*hi2) * 2); \
        short4v w1 = *(const short4v*)(bKT + ((32 + l31) * 68 + 32 + 8 + 4*hi2) * 2); \
        agg1 = mfmah(pa[2], cat44(w0, w1), agg1);                              \
        short4v v2 = *(const short4v*)(bKT + (l31 * 68 + 48 + 4*hi2) * 2);     \
        short4v v3 = *(const short4v*)(bKT + (l31 * 68 + 48 + 8 + 4*hi2) * 2); \
        agg0 = mfmah(pa[3], cat44(v2, v3), agg0);                              \
        short4v w2 = *(const short4v*)(bKT + ((32 + l31) * 68 + 48 + 4*hi2) * 2); \
        short4v w3 = *(const short4v*)(bKT + ((32 + l31) * 68 + 48 + 8 + 4*hi2) * 2); \
        agg1 = mfmah(pa[3], cat44(w2, w3), agg1);                              \
    }                                                                          \
  }

    // ---- prologue: stage tile 0 into buf0 ----
    {
        f32x4 l0, l1;
        STAGE_LOAD(0, l0, l1)
        STAGE_CONVERT(l0, l1)
        STAGE_LDS_WRITE(smem)
    }
    __syncthreads();

    float lp4[4] = {0.f, 0.f, 0.f, 0.f};
    f32x16 agg0, agg1;
    #pragma unroll
    for (int i = 0; i < 16; ++i) { agg0[i] = 0.f; agg1[i] = 0.f; }

    unsigned bo = 0;
    for (int mt = 0; mt < 8; ++mt) {
        // T14: issue next-tile staging loads first (longest latency)
        f32x4 p0, p1;
        if (mt < 7) STAGE_LOAD((mt + 1) * 64, p0, p1)

        PROCESS_TILE(smem + bo, mt * 64)

        // write next tile into the idle buffer; prev-iter barrier guarantees
        // all waves are done reading it, this iter's barrier publishes it
        if (mt < 7) {
            STAGE_CONVERT(p0, p1)
            STAGE_LDS_WRITE(smem + (bo ^ BUFSZ))
        }
        __syncthreads();
        bo ^= BUFSZ;
    }

    // ---- epilogue ----
    float lpart = (lp4[0] + lp4[1]) + (lp4[2] + lp4[3]);
    float lf = lpart + __shfl_xor(lpart, 32);
    if (hi2 == 0) linvLDS[32 * w + l31] = 0.125f / lf;   // fold post-softmax 1/8
    __syncthreads();

    // normalized agg -> sA [256][68] (fp16 hi only)
    #pragma unroll
    for (int r = 0; r < 16; ++r) {
        int row = 32 * w + (r & 3) + 8 * (r >> 2) + 4 * hi2;
        float nv = linvLDS[row];
        _Float16 h0 = (_Float16)(agg0[r] * nv);
        _Float16 h1 = (_Float16)(agg1[r] * nv);
        *(short*)(sA + (row * 68 + l31) * 2)      = __builtin_bit_cast(short, h0);
        *(short*)(sA + (row * 68 + 32 + l31) * 2) = __builtin_bit_cast(short, h1);
    }
    __syncthreads();

    short8v gH[4];
    #pragma unroll
    for (int ks = 0; ks < 4; ++ks) {
        short4v a0 = *(const short4v*)(sA + ((32*w + l31) * 68 + ks*16 + hi2*8) * 2);
        short4v a1 = *(const short4v*)(sA + ((32*w + l31) * 68 + ks*16 + hi2*8 + 4) * 2);
        gH[ks] = cat44(a0, a1);
    }

    // out = relu(aggN * W^T): B = W row per lane, 2-term W-split (Wh + Wl)
    #pragma unroll
    for (int ob = 0; ob < 2; ++ob) {
        short8v wHreg[4], wLreg[4];
        #pragma unroll
        for (int ks = 0; ks < 4; ++ks) {
            const float* wp = W + (size_t)(ob * 32 + l31) * FF + ks * 16 + hi2 * 8;
            f32x4 wa = *(const f32x4*)(wp);
            f32x4 wb = *(const f32x4*)(wp + 4);
            short4v h0, l0, h1, l1;
            cvt4h(wa, h0, l0);
            cvt4h(wb, h1, l1);
            wHreg[ks] = cat44(h0, h1);
            wLreg[ks] = cat44(l0, l1);
        }
        f32x16 oc;
        #pragma unroll
        for (int i = 0; i < 16; ++i) oc[i] = 0.f;
        #pragma unroll
        for (int ks = 0; ks < 4; ++ks) {
            oc = mfmah(gH[ks], wHreg[ks], oc);
            oc = mfmah(gH[ks], wLreg[ks], oc);
        }
        #pragma unroll
        for (int r = 0; r < 16; ++r) {
            int row = 32 * w + (r & 3) + 8 * (r >> 2) + 4 * hi2;
            out[((size_t)(b * NN + n0 + row) * TT + t) * FF + 32 * ob + l31] = fmaxf(oc[r], 0.f);
        }
    }
#undef STAGE_LOAD
#undef STAGE_CONVERT
#undef STAGE_LDS_WRITE
#undef PROCESS_TILE
}

extern "C" void kernel_launch(void* const* d_in, const int* in_sizes, int n_in,
                              void* d_out, int out_size, void* d_ws, size_t ws_size,
                              hipStream_t stream) {
    const float* x   = (const float*)d_in[0];
    const float* adj = (const float*)d_in[1];
    const float* W   = (const float*)d_in[2];
    float* outp = (float*)d_out;

    sgcn20<<<dim3(768), dim3(512), 0, stream>>>(x, adj, W, outp);
}